// Round 1
// baseline (112.782 us; speedup 1.0000x reference)
//
#include <hip/hip_runtime.h>
#include <hip/hip_bf16.h>

#define D 128

// ---------------------------------------------------------------------------
// Kernel 1 (1 block, 128 threads): b_w = b_alpha^T @ W_alpha (per-column),
// a_w = a_alpha^T @ W_alpha, c = a_w . X[0].
// ---------------------------------------------------------------------------
__global__ __launch_bounds__(128) void prep_kernel(
    const float* __restrict__ X,
    const float* __restrict__ W_alpha,
    const float* __restrict__ a_alpha,
    const float* __restrict__ b_alpha,
    float* __restrict__ bw_out,   // [D]
    float* __restrict__ c_out)    // [1]
{
    const int k = threadIdx.x;            // output column 0..127
    float aw = 0.f, bw = 0.f;
    #pragma unroll 4
    for (int i = 0; i < D; ++i) {
        const float w = W_alpha[i * D + k];   // coalesced across k
        aw = fmaf(a_alpha[i], w, aw);
        bw = fmaf(b_alpha[i], w, bw);
    }
    bw_out[k] = bw;

    // c = sum_k aw_k * X[0][k] : block reduction over 128 threads (2 waves)
    float part = aw * X[k];
    #pragma unroll
    for (int m = 32; m >= 1; m >>= 1) part += __shfl_xor(part, m, 64);
    __shared__ float wsum[2];
    if ((k & 63) == 0) wsum[k >> 6] = part;
    __syncthreads();
    if (k == 0) c_out[0] = wsum[0] + wsum[1];
}

// ---------------------------------------------------------------------------
// Kernel 2 (main pass): single read of X. 256 threads/block; each 32-lane
// subgroup owns one row per iteration (32 x float4 = 512 B), computes
// dot(X[row], b_w) via shfl butterfly, alpha = exp(dot + c), and accumulates
// alpha * X[row] into per-thread (per-column) float accumulators.
// Block partials (128 doubles + 1 double) go to workspace; reduction order is
// fixed -> deterministic.
// ---------------------------------------------------------------------------
__global__ __launch_bounds__(256) void main_pass_kernel(
    const float* __restrict__ X,
    const float* __restrict__ bw,
    const float* __restrict__ c_ptr,
    double* __restrict__ partial_wsum,    // [gridDim.x][D]
    double* __restrict__ partial_alpha,   // [gridDim.x]
    int nrows)
{
    const int t    = threadIdx.x;
    const int col4 = t & 31;   // which float4 of the row
    const int rg   = t >> 5;   // row-group 0..7 within the block

    const float4 bwv = reinterpret_cast<const float4*>(bw)[col4];
    const float  c   = *c_ptr;

    float a0 = 0.f, a1 = 0.f, a2 = 0.f, a3 = 0.f;
    float aacc = 0.f;

    const int ntiles = (nrows + 7) >> 3;
    const float4* __restrict__ X4 = reinterpret_cast<const float4*>(X);

    for (int tile = blockIdx.x; tile < ntiles; tile += gridDim.x) {
        const int row = tile * 8 + rg;
        if (row < nrows) {
            const float4 x = X4[(size_t)row * 32 + col4];
            float dot = fmaf(x.x, bwv.x,
                        fmaf(x.y, bwv.y,
                        fmaf(x.z, bwv.z, x.w * bwv.w)));
            // reduce across the 32 lanes of this row-group (masks <=16 stay
            // inside each aligned 32-lane half of the wave64)
            #pragma unroll
            for (int m = 16; m >= 1; m >>= 1) dot += __shfl_xor(dot, m, 64);
            const float alpha = expf(dot + c);
            if (col4 == 0) aacc += alpha;    // one lane per row-group
            a0 = fmaf(alpha, x.x, a0);
            a1 = fmaf(alpha, x.y, a1);
            a2 = fmaf(alpha, x.z, a2);
            a3 = fmaf(alpha, x.w, a3);
        }
    }

    // -------- block reduction (8 row-groups -> one 128-vector) --------
    __shared__ double red[8][32][4];   // 8 KB
    __shared__ double reda[8];
    red[rg][col4][0] = (double)a0;
    red[rg][col4][1] = (double)a1;
    red[rg][col4][2] = (double)a2;
    red[rg][col4][3] = (double)a3;
    if (col4 == 0) reda[rg] = (double)aacc;
    __syncthreads();

    if (t < D) {
        double s = 0.0;
        #pragma unroll
        for (int r = 0; r < 8; ++r) s += red[r][t >> 2][t & 3];
        partial_wsum[(size_t)blockIdx.x * D + t] = s;
    }
    if (t == 0) {
        double s = 0.0;
        #pragma unroll
        for (int r = 0; r < 8; ++r) s += reda[r];
        partial_alpha[blockIdx.x] = s;
    }
}

// ---------------------------------------------------------------------------
// Kernel 3 (1 block, 128 threads): reduce block partials, normalize,
// out = (wsum/asum) @ W_sum.
// ---------------------------------------------------------------------------
__global__ __launch_bounds__(128) void finalize_kernel(
    const double* __restrict__ partial_wsum,
    const double* __restrict__ partial_alpha,
    const float* __restrict__ W_sum,
    float* __restrict__ out,
    int nblocks)
{
    const int j = threadIdx.x;

    double ws = 0.0;
    #pragma unroll 4
    for (int b = 0; b < nblocks; ++b)
        ws += partial_wsum[(size_t)b * D + j];    // coalesced across j

    double ap = 0.0;
    for (int b = j; b < nblocks; b += D) ap += partial_alpha[b];
    __shared__ double apsh[D];
    apsh[j] = ap;
    __syncthreads();
    __shared__ double asum_sh;
    if (j == 0) {
        double s = 0.0;
        for (int i = 0; i < D; ++i) s += apsh[i];
        asum_sh = s;
    }
    __syncthreads();

    __shared__ float s_sh[D];
    s_sh[j] = (float)(ws / asum_sh);
    __syncthreads();

    // out[j] = sum_k s[k] * W_sum[k][j]  (coalesced across j for each k)
    float o = 0.f;
    #pragma unroll 4
    for (int k = 0; k < D; ++k) o = fmaf(s_sh[k], W_sum[k * D + j], o);
    out[j] = o;
}

// ---------------------------------------------------------------------------
extern "C" void kernel_launch(void* const* d_in, const int* in_sizes, int n_in,
                              void* d_out, int out_size, void* d_ws, size_t ws_size,
                              hipStream_t stream) {
    const float* X       = (const float*)d_in[0];
    const float* W_sum   = (const float*)d_in[1];
    const float* W_alpha = (const float*)d_in[2];
    const float* a_alpha = (const float*)d_in[3];
    const float* b_alpha = (const float*)d_in[4];
    float* out = (float*)d_out;

    const int nrows = in_sizes[0] / D;   // 200000

    // grid size for the main pass; shrink if the workspace is small
    int NB = 1024;
    while (NB > 64 &&
           ((size_t)NB * D * sizeof(double) + (size_t)NB * sizeof(double)
            + (D + 1) * sizeof(float) + 64) > ws_size)
        NB >>= 1;

    char* ws = (char*)d_ws;
    double* partial_wsum  = (double*)ws;
    double* partial_alpha = (double*)(ws + (size_t)NB * D * sizeof(double));
    float*  bw            = (float*)(ws + (size_t)NB * D * sizeof(double)
                                        + (size_t)NB * sizeof(double));
    float*  cv            = bw + D;

    prep_kernel<<<1, 128, 0, stream>>>(X, W_alpha, a_alpha, b_alpha, bw, cv);
    main_pass_kernel<<<NB, 256, 0, stream>>>(X, bw, cv, partial_wsum,
                                             partial_alpha, nrows);
    finalize_kernel<<<1, 128, 0, stream>>>(partial_wsum, partial_alpha,
                                           W_sum, out, NB);
}

// Round 2
// 61.811 us; speedup vs baseline: 1.8246x; 1.8246x over previous
//
#include <hip/hip_runtime.h>
#include <hip/hip_bf16.h>

#define D 128

// ---------------------------------------------------------------------------
// Kernel 1 (1 block, 1024 threads): b_w = b_alpha^T @ W_alpha,
// a_w = a_alpha^T @ W_alpha, c = a_w . X[0].
// 8 thread-groups each sum 16 of the 128 K-terms -> LDS reduce.
// ---------------------------------------------------------------------------
__global__ __launch_bounds__(1024) void prep_kernel(
    const float* __restrict__ X,
    const float* __restrict__ W_alpha,
    const float* __restrict__ a_alpha,
    const float* __restrict__ b_alpha,
    float* __restrict__ bw_out,   // [D]
    float* __restrict__ c_out)    // [1]
{
    const int t = threadIdx.x;
    const int k = t & 127;        // output column
    const int g = t >> 7;         // 0..7: which 16-row chunk of the sum

    float aw = 0.f, bw = 0.f;
    #pragma unroll
    for (int i = g * 16; i < g * 16 + 16; ++i) {
        const float w = W_alpha[i * D + k];   // coalesced across k
        aw = fmaf(a_alpha[i], w, aw);
        bw = fmaf(b_alpha[i], w, bw);
    }
    __shared__ float raw[8][D], rbw[8][D];
    raw[g][k] = aw;
    rbw[g][k] = bw;
    __syncthreads();

    __shared__ float wsum[2];
    if (t < D) {
        float A = 0.f, B = 0.f;
        #pragma unroll
        for (int r = 0; r < 8; ++r) { A += raw[r][t]; B += rbw[r][t]; }
        bw_out[t] = B;
        float part = A * X[t];
        #pragma unroll
        for (int m = 32; m >= 1; m >>= 1) part += __shfl_xor(part, m, 64);
        if ((t & 63) == 0) wsum[t >> 6] = part;
    }
    __syncthreads();
    if (t == 0) c_out[0] = wsum[0] + wsum[1];
}

// ---------------------------------------------------------------------------
// Kernel 2 (main pass): single read of X. 256 threads/block; each 32-lane
// subgroup owns one row per iteration (32 x float4 = 512 B), computes
// dot(X[row], b_w) via shfl butterfly, alpha = exp(dot + c), and accumulates
// alpha * X[row] into per-thread (per-column) float accumulators.
// ---------------------------------------------------------------------------
__global__ __launch_bounds__(256) void main_pass_kernel(
    const float* __restrict__ X,
    const float* __restrict__ bw,
    const float* __restrict__ c_ptr,
    double* __restrict__ partial_wsum,    // [gridDim.x][D]
    double* __restrict__ partial_alpha,   // [gridDim.x]
    int nrows)
{
    const int t    = threadIdx.x;
    const int col4 = t & 31;   // which float4 of the row
    const int rg   = t >> 5;   // row-group 0..7 within the block

    const float4 bwv = reinterpret_cast<const float4*>(bw)[col4];
    const float  c   = *c_ptr;

    float a0 = 0.f, a1 = 0.f, a2 = 0.f, a3 = 0.f;
    float aacc = 0.f;

    const int ntiles = (nrows + 7) >> 3;
    const float4* __restrict__ X4 = reinterpret_cast<const float4*>(X);

    for (int tile = blockIdx.x; tile < ntiles; tile += gridDim.x) {
        const int row = tile * 8 + rg;
        if (row < nrows) {
            const float4 x = X4[(size_t)row * 32 + col4];
            float dot = fmaf(x.x, bwv.x,
                        fmaf(x.y, bwv.y,
                        fmaf(x.z, bwv.z, x.w * bwv.w)));
            #pragma unroll
            for (int m = 16; m >= 1; m >>= 1) dot += __shfl_xor(dot, m, 64);
            const float alpha = expf(dot + c);
            if (col4 == 0) aacc += alpha;    // one lane per row-group
            a0 = fmaf(alpha, x.x, a0);
            a1 = fmaf(alpha, x.y, a1);
            a2 = fmaf(alpha, x.z, a2);
            a3 = fmaf(alpha, x.w, a3);
        }
    }

    // -------- block reduction (8 row-groups -> one 128-vector) --------
    __shared__ double red[8][32][4];   // 8 KB
    __shared__ double reda[8];
    red[rg][col4][0] = (double)a0;
    red[rg][col4][1] = (double)a1;
    red[rg][col4][2] = (double)a2;
    red[rg][col4][3] = (double)a3;
    if (col4 == 0) reda[rg] = (double)aacc;
    __syncthreads();

    if (t < D) {
        double s = 0.0;
        #pragma unroll
        for (int r = 0; r < 8; ++r) s += red[r][t >> 2][t & 3];
        partial_wsum[(size_t)blockIdx.x * D + t] = s;
    }
    if (t == 0) {
        double s = 0.0;
        #pragma unroll
        for (int r = 0; r < 8; ++r) s += reda[r];
        partial_alpha[blockIdx.x] = s;
    }
}

// ---------------------------------------------------------------------------
// Kernel 3 (1 block, 1024 threads): reduce block partials (parallel, fixed
// order -> deterministic), normalize, out = (wsum/asum) @ W_sum.
// ---------------------------------------------------------------------------
__global__ __launch_bounds__(1024) void finalize_kernel(
    const double* __restrict__ partial_wsum,
    const double* __restrict__ partial_alpha,
    const float* __restrict__ W_sum,
    float* __restrict__ out,
    int nblocks)
{
    const int t = threadIdx.x;
    const int k = t & 127;
    const int g = t >> 7;     // 0..7

    // ---- weighted-sum partials: 8 groups stride the rows ----
    double ws = 0.0;
    for (int r = g; r < nblocks; r += 8)
        ws += partial_wsum[(size_t)r * D + k];   // coalesced across k
    __shared__ double red[8][D];    // 8 KB
    red[g][k] = ws;

    // ---- alpha partials: all 1024 threads stride, then tree reduce ----
    double ap = 0.0;
    for (int i = t; i < nblocks; i += 1024) ap += partial_alpha[i];
    __shared__ double reda[1024];   // 8 KB
    reda[t] = ap;
    __syncthreads();
    #pragma unroll
    for (int s = 512; s >= 1; s >>= 1) {
        if (t < s) reda[t] += reda[t + s];
        __syncthreads();
    }
    const double asum = reda[0];

    __shared__ float s_sh[D];
    if (t < D) {
        double s = 0.0;
        #pragma unroll
        for (int r = 0; r < 8; ++r) s += red[r][t];
        s_sh[t] = (float)(s / asum);
    }
    __syncthreads();

    // ---- out[j] = sum_k s[k] * W_sum[k][j], split over the 8 groups ----
    float o = 0.f;
    #pragma unroll
    for (int kk = g * 16; kk < g * 16 + 16; ++kk)
        o = fmaf(s_sh[kk], W_sum[kk * D + k], o);   // coalesced across k
    __shared__ float rout[8][D];    // 4 KB
    rout[g][k] = o;
    __syncthreads();
    if (t < D) {
        float s = 0.f;
        #pragma unroll
        for (int r = 0; r < 8; ++r) s += rout[r][t];
        out[t] = s;
    }
}

// ---------------------------------------------------------------------------
extern "C" void kernel_launch(void* const* d_in, const int* in_sizes, int n_in,
                              void* d_out, int out_size, void* d_ws, size_t ws_size,
                              hipStream_t stream) {
    const float* X       = (const float*)d_in[0];
    const float* W_sum   = (const float*)d_in[1];
    const float* W_alpha = (const float*)d_in[2];
    const float* a_alpha = (const float*)d_in[3];
    const float* b_alpha = (const float*)d_in[4];
    float* out = (float*)d_out;

    const int nrows = in_sizes[0] / D;   // 200000

    // grid size for the main pass; shrink if the workspace is small
    int NB = 1024;
    while (NB > 64 &&
           ((size_t)NB * D * sizeof(double) + (size_t)NB * sizeof(double)
            + (D + 1) * sizeof(float) + 64) > ws_size)
        NB >>= 1;

    char* ws = (char*)d_ws;
    double* partial_wsum  = (double*)ws;
    double* partial_alpha = (double*)(ws + (size_t)NB * D * sizeof(double));
    float*  bw            = (float*)(ws + (size_t)NB * D * sizeof(double)
                                        + (size_t)NB * sizeof(double));
    float*  cv            = bw + D;

    prep_kernel<<<1, 1024, 0, stream>>>(X, W_alpha, a_alpha, b_alpha, bw, cv);
    main_pass_kernel<<<NB, 256, 0, stream>>>(X, bw, cv, partial_wsum,
                                             partial_alpha, nrows);
    finalize_kernel<<<1, 1024, 0, stream>>>(partial_wsum, partial_alpha,
                                            W_sum, out, NB);
}

// Round 3
// 35.930 us; speedup vs baseline: 3.1389x; 1.7203x over previous
//
#include <hip/hip_runtime.h>
#include <hip/hip_bf16.h>

#define D 128

// ---------------------------------------------------------------------------
// Kernel 1 (1 block, 1024 threads): b_w = b_alpha^T @ W_alpha,
// a_w = a_alpha^T @ W_alpha, c = a_w . X[0].
// ---------------------------------------------------------------------------
__global__ __launch_bounds__(1024) void prep_kernel(
    const float* __restrict__ X,
    const float* __restrict__ W_alpha,
    const float* __restrict__ a_alpha,
    const float* __restrict__ b_alpha,
    float* __restrict__ bw_out,   // [D]
    float* __restrict__ c_out)    // [1]
{
    const int t = threadIdx.x;
    const int k = t & 127;        // output column
    const int g = t >> 7;         // 0..7: which 16-row chunk of the sum

    float aw = 0.f, bw = 0.f;
    #pragma unroll
    for (int i = g * 16; i < g * 16 + 16; ++i) {
        const float w = W_alpha[i * D + k];   // coalesced across k
        aw = fmaf(a_alpha[i], w, aw);
        bw = fmaf(b_alpha[i], w, bw);
    }
    __shared__ float raw[8][D], rbw[8][D];
    raw[g][k] = aw;
    rbw[g][k] = bw;
    __syncthreads();

    __shared__ float wsum[2];
    if (t < D) {
        float A = 0.f, B = 0.f;
        #pragma unroll
        for (int r = 0; r < 8; ++r) { A += raw[r][t]; B += rbw[r][t]; }
        bw_out[t] = B;
        float part = A * X[t];
        #pragma unroll
        for (int m = 32; m >= 1; m >>= 1) part += __shfl_xor(part, m, 64);
        if ((t & 63) == 0) wsum[t >> 6] = part;
    }
    __syncthreads();
    if (t == 0) c_out[0] = wsum[0] + wsum[1];
}

// ---------------------------------------------------------------------------
// Kernel 2 (main pass): single read of X. 256 threads/block; each 32-lane
// subgroup owns TWO rows per iteration (2 independent load+reduce chains for
// ILP). dot via shfl butterfly, alpha = __expf(dot + c), accumulate
// alpha * X[row] into per-thread float accumulators.
// ---------------------------------------------------------------------------
__global__ __launch_bounds__(256) void main_pass_kernel(
    const float* __restrict__ X,
    const float* __restrict__ bw,
    const float* __restrict__ c_ptr,
    float* __restrict__ partial_wsum,    // [gridDim.x][D]
    float* __restrict__ partial_alpha,   // [gridDim.x]
    int nrows)
{
    const int t    = threadIdx.x;
    const int col4 = t & 31;   // which float4 of the row
    const int rg   = t >> 5;   // row-group 0..7 within the block

    const float4 bwv = reinterpret_cast<const float4*>(bw)[col4];
    const float  c   = *c_ptr;

    float a0 = 0.f, a1 = 0.f, a2 = 0.f, a3 = 0.f;
    float aacc = 0.f;

    const int ntiles = (nrows + 15) >> 4;   // 16 rows per block-iteration
    const float4* __restrict__ X4 = reinterpret_cast<const float4*>(X);

    for (int tile = blockIdx.x; tile < ntiles; tile += gridDim.x) {
        const int r0 = tile * 16 + rg * 2;
        const int r1 = r0 + 1;
        const bool v0 = r0 < nrows, v1 = r1 < nrows;
        float4 x0 = v0 ? X4[(size_t)r0 * 32 + col4] : make_float4(0.f,0.f,0.f,0.f);
        float4 x1 = v1 ? X4[(size_t)r1 * 32 + col4] : make_float4(0.f,0.f,0.f,0.f);

        float d0 = fmaf(x0.x, bwv.x, fmaf(x0.y, bwv.y, fmaf(x0.z, bwv.z, x0.w * bwv.w)));
        float d1 = fmaf(x1.x, bwv.x, fmaf(x1.y, bwv.y, fmaf(x1.z, bwv.z, x1.w * bwv.w)));
        #pragma unroll
        for (int m = 16; m >= 1; m >>= 1) {
            d0 += __shfl_xor(d0, m, 64);
            d1 += __shfl_xor(d1, m, 64);
        }
        const float al0 = v0 ? __expf(d0 + c) : 0.f;
        const float al1 = v1 ? __expf(d1 + c) : 0.f;
        if (col4 == 0) aacc += al0 + al1;
        a0 = fmaf(al0, x0.x, fmaf(al1, x1.x, a0));
        a1 = fmaf(al0, x0.y, fmaf(al1, x1.y, a1));
        a2 = fmaf(al0, x0.z, fmaf(al1, x1.z, a2));
        a3 = fmaf(al0, x0.w, fmaf(al1, x1.w, a3));
    }

    // -------- block reduction (8 row-groups -> one 128-vector) --------
    __shared__ float red[8][32][4];   // 4 KB
    __shared__ float reda[8];
    red[rg][col4][0] = a0;
    red[rg][col4][1] = a1;
    red[rg][col4][2] = a2;
    red[rg][col4][3] = a3;
    if (col4 == 0) reda[rg] = aacc;
    __syncthreads();

    if (t < D) {
        double s = 0.0;
        #pragma unroll
        for (int r = 0; r < 8; ++r) s += (double)red[r][t >> 2][t & 3];
        partial_wsum[(size_t)blockIdx.x * D + t] = (float)s;
    }
    if (t == 0) {
        double s = 0.0;
        #pragma unroll
        for (int r = 0; r < 8; ++r) s += (double)reda[r];
        partial_alpha[blockIdx.x] = (float)s;
    }
}

// ---------------------------------------------------------------------------
// Kernel 3 (NB2 blocks, 512 threads): tree-reduce block partials.
// Block b sums rows {b + NB2*j} -> mid[b][D] (double) + mida[b].
// ---------------------------------------------------------------------------
__global__ __launch_bounds__(512) void reduce1_kernel(
    const float* __restrict__ partial_wsum,
    const float* __restrict__ partial_alpha,
    double* __restrict__ mid,     // [NB2][D]
    double* __restrict__ mida,    // [NB2]
    int NB, int NB2)
{
    const int b  = blockIdx.x;
    const int t  = threadIdx.x;
    const int k  = t & 127;
    const int rs = t >> 7;        // 0..3
    const int nper = NB / NB2;

    double s = 0.0;
    for (int j = rs; j < nper; j += 4)
        s += (double)partial_wsum[(size_t)(b + NB2 * j) * D + k];  // coalesced
    __shared__ double red[4][D];  // 4 KB
    red[rs][k] = s;

    __shared__ double reda[64];
    if (t < nper && t < 64) {
        double sa = 0.0;
        for (int j = t; j < nper; j += 64) sa += (double)partial_alpha[b + NB2 * j];
        reda[t] = sa;
    }
    __syncthreads();

    if (t < D)
        mid[(size_t)b * D + t] = red[0][t] + red[1][t] + red[2][t] + red[3][t];
    if (t == 0) {
        double sa = 0.0;
        const int lim = nper < 64 ? nper : 64;
        for (int i = 0; i < lim; ++i) sa += reda[i];
        mida[b] = sa;
    }
}

// ---------------------------------------------------------------------------
// Kernel 4 (1 block, 1024 threads): final reduce, normalize, @ W_sum.
// ---------------------------------------------------------------------------
__global__ __launch_bounds__(1024) void final_kernel(
    const double* __restrict__ mid,
    const double* __restrict__ mida,
    const float* __restrict__ W_sum,
    float* __restrict__ out,
    int NB2)
{
    const int t = threadIdx.x;
    const int k = t & 127;
    const int g = t >> 7;     // 0..7

    double ws = 0.0;
    for (int j = g; j < NB2; j += 8)
        ws += mid[(size_t)j * D + k];   // coalesced across k
    __shared__ double red[8][D];    // 8 KB
    red[g][k] = ws;

    __shared__ double reda[64];
    if (t < NB2) reda[t] = mida[t];
    __syncthreads();
    __shared__ double asum_sh;
    if (t == 0) {
        double a = 0.0;
        for (int i = 0; i < NB2; ++i) a += reda[i];
        asum_sh = a;
    }
    __syncthreads();

    __shared__ float s_sh[D];
    if (t < D) {
        double s = 0.0;
        #pragma unroll
        for (int r = 0; r < 8; ++r) s += red[r][t];
        s_sh[t] = (float)(s / asum_sh);
    }
    __syncthreads();

    // out[j] = sum_k s[k] * W_sum[k][j], split over the 8 groups
    float o = 0.f;
    #pragma unroll
    for (int kk = g * 16; kk < g * 16 + 16; ++kk)
        o = fmaf(s_sh[kk], W_sum[kk * D + k], o);   // coalesced across k
    __shared__ float rout[8][D];    // 4 KB
    rout[g][k] = o;
    __syncthreads();
    if (t < D) {
        float s = 0.f;
        #pragma unroll
        for (int r = 0; r < 8; ++r) s += rout[r][t];
        out[t] = s;
    }
}

// ---------------------------------------------------------------------------
extern "C" void kernel_launch(void* const* d_in, const int* in_sizes, int n_in,
                              void* d_out, int out_size, void* d_ws, size_t ws_size,
                              hipStream_t stream) {
    const float* X       = (const float*)d_in[0];
    const float* W_sum   = (const float*)d_in[1];
    const float* W_alpha = (const float*)d_in[2];
    const float* a_alpha = (const float*)d_in[3];
    const float* b_alpha = (const float*)d_in[4];
    float* out = (float*)d_out;

    const int nrows = in_sizes[0] / D;   // 200000
    const int NB2 = 64;

    // grid size for the main pass; shrink if the workspace is small
    int NB = 2048;
    auto need = [&](int nb) {
        return (size_t)nb * D * sizeof(float)        // partial_wsum
             + (size_t)nb * sizeof(float)            // partial_alpha
             + (size_t)NB2 * D * sizeof(double)      // mid
             + (size_t)NB2 * sizeof(double)          // mida
             + (D + 1) * sizeof(float) + 256;
    };
    while (NB > NB2 && need(NB) > ws_size) NB >>= 1;

    char* ws = (char*)d_ws;
    float*  partial_wsum  = (float*)ws;
    float*  partial_alpha = (float*)(ws + (size_t)NB * D * sizeof(float));
    double* mid           = (double*)(ws + (size_t)NB * D * sizeof(float)
                                         + (size_t)NB * sizeof(float) + 248 - ((size_t)NB * (D + 1) * sizeof(float) + 248) % 8);
    // simpler deterministic aligned layout:
    size_t off = (size_t)NB * (D + 1) * sizeof(float);
    off = (off + 255) & ~(size_t)255;
    mid = (double*)(ws + off);
    double* mida = mid + (size_t)NB2 * D;
    float*  bw   = (float*)(mida + NB2);
    float*  cv   = bw + D;

    prep_kernel<<<1, 1024, 0, stream>>>(X, W_alpha, a_alpha, b_alpha, bw, cv);
    main_pass_kernel<<<NB, 256, 0, stream>>>(X, bw, cv, partial_wsum,
                                             partial_alpha, nrows);
    reduce1_kernel<<<NB2, 512, 0, stream>>>(partial_wsum, partial_alpha,
                                            mid, mida, NB, NB2);
    final_kernel<<<1, 1024, 0, stream>>>(mid, mida, W_sum, out, NB2);
}